// Round 3
// baseline (1082.160 us; speedup 1.0000x reference)
//
#include <hip/hip_runtime.h>
#include <cstdint>
#include <cstddef>

// Problem constants (B,S,HID,NH,IM,E fixed by the reference)
#define B_    4
#define S_    2048
#define HID_  1024
#define NH_   4
#define HD_   256     // HID/NH
#define IM_   2048
#define E_    4
#define M_    8192    // B_*S_ tokens
#define NHG_  4       // heads per attention group

typedef __bf16 bf16x8 __attribute__((ext_vector_type(8)));
typedef float  f32x4  __attribute__((ext_vector_type(4)));

__device__ __forceinline__ unsigned short f32_to_bf16(float f) {
  unsigned int u = __float_as_uint(f);
  u += 0x7fffu + ((u >> 16) & 1u);   // round-to-nearest-even
  return (unsigned short)(u >> 16);
}

// async 16B global->LDS DMA (global_load_lds_dwordx4). LDS dest is
// wave-uniform base + lane*16 -> LDS layout contiguous in lane order.
__device__ __forceinline__ void gload16(const unsigned short* g, unsigned short* l) {
  __builtin_amdgcn_global_load_lds(
      (const __attribute__((address_space(1))) void*)g,
      (__attribute__((address_space(3))) void*)l, 16, 0, 0);
}

template<int N> __device__ __forceinline__ void vwait() {
  if constexpr (N == 0)      asm volatile("s_waitcnt vmcnt(0)" ::: "memory");
  else if constexpr (N == 2) asm volatile("s_waitcnt vmcnt(2)" ::: "memory");
  else if constexpr (N == 6) asm volatile("s_waitcnt vmcnt(6)" ::: "memory");
  else                       asm volatile("s_waitcnt vmcnt(8)" ::: "memory");
}
__device__ __forceinline__ void lgk0() {
  asm volatile("s_waitcnt lgkmcnt(0)" ::: "memory");
}

// XCD-aware swizzle: contiguous y-bands per XCD.
__device__ __forceinline__ void swizzle_xy(int& bx, int& by) {
  const int gx = gridDim.x, gy = gridDim.y;
  const int flat = blockIdx.x + blockIdx.y * gx;
  const int xcd = flat & 7, i = flat >> 3;
  const int rpx = gy >> 3;          // y-rows per XCD
  bx = i % gx;
  by = xcd * rpx + i / gx;
}

// ---------------- epilogue variants (generic single-B GEMM) ----------------
#define EPI_F32      0   // C fp32 (attention scores), batched via strideCz
#define EPI_VT       2   // write V^T [b][h][d][s] bf16
#define EPI_PV_O     3   // write attn O into [token][h*HD+n] bf16
#define EPI_WO       4   // out2 = add_src + acc  (fallback)
#define EPI_DOWN     5   // out2 += acc  (fallback path)

struct EpiAux {
  float* c_f32;
  unsigned short* c_bf16;
  const float* add_src;       // hidden (WO)
  float* out2;                // d_out (WO/DOWN)
  long long strideCz;
  int ldc;
};

// Generic batched GEMM: C[z] = A[z] (MxK, row-major, lda) @ B[z]^T.
// 128x128 tile, BK=32, 4 waves x (4x4) 16x16x32 bf16 MFMA fragments.
// Double-buffered LDS, one-iteration-ahead async global_load_lds prefetch.
template<int EPI>
__global__ __launch_bounds__(256) void gemm_bf16k(
    const unsigned short* __restrict__ A, int lda, long long sAo, long long sAi, int zbA,
    const unsigned short* __restrict__ B, int ldb, long long sBo, long long sBi, int zbB,
    int zshift, int zmask, int zbC, int K, EpiAux aux)
{
  __shared__ unsigned short As[2][128 * 32];
  __shared__ unsigned short Bs[2][128 * 32];

  const int t = threadIdx.x;
  int bx, by;
  swizzle_xy(bx, by);
  const int m0 = by * 128, n0 = bx * 128;
  const int z  = blockIdx.z;
  const int zA = z + zbA, zB = z + zbB, zC = z + zbC;
  const unsigned short* Ab = A + (long long)(zA >> zshift) * sAo + (long long)(zA & zmask) * sAi;
  const unsigned short* Bb = B + (long long)(zB >> zshift) * sBo + (long long)(zB & zmask) * sBi;

  const int lane = t & 63, wave = t >> 6;
  const int wm = (wave >> 1) * 64, wn = (wave & 1) * 64;
  const int lrow = lane & 15, quad = lane >> 4;

  f32x4 acc[4][4] = {};

  const int srow = lane >> 2;         // 0..15
  const int sko  = (lane & 3) * 8;    // k-elem 0/8/16/24
  const unsigned short* aRow0 = Ab + (long long)(m0 + wave * 16       + srow) * lda + sko;
  const unsigned short* aRow1 = Ab + (long long)(m0 + (wave + 4) * 16 + srow) * lda + sko;
  const unsigned short* bRow0 = Bb + (long long)(n0 + wave * 16       + srow) * ldb + sko;
  const unsigned short* bRow1 = Bb + (long long)(n0 + (wave + 4) * 16 + srow) * ldb + sko;
  const int dst0 = (wave * 16) * 32, dst1 = ((wave + 4) * 16) * 32;

  gload16(aRow0, &As[0][dst0]);
  gload16(aRow1, &As[0][dst1]);
  gload16(bRow0, &Bs[0][dst0]);
  gload16(bRow1, &Bs[0][dst1]);

  int cur = 0;
  for (int kk = 0; kk < K; kk += 32, cur ^= 1) {
    __syncthreads();
    if (kk + 32 < K) {
      const int nxt = cur ^ 1, k2 = kk + 32;
      gload16(aRow0 + k2, &As[nxt][dst0]);
      gload16(aRow1 + k2, &As[nxt][dst1]);
      gload16(bRow0 + k2, &Bs[nxt][dst0]);
      gload16(bRow1 + k2, &Bs[nxt][dst1]);
    }
    bf16x8 af[4], bfr[4];
    #pragma unroll
    for (int i = 0; i < 4; ++i) {
      af[i]  = *reinterpret_cast<const bf16x8*>(&As[cur][(wm + i * 16 + lrow) * 32 + quad * 8]);
      bfr[i] = *reinterpret_cast<const bf16x8*>(&Bs[cur][(wn + i * 16 + lrow) * 32 + quad * 8]);
    }
    #pragma unroll
    for (int i = 0; i < 4; ++i)
      #pragma unroll
      for (int j = 0; j < 4; ++j)
        acc[i][j] = __builtin_amdgcn_mfma_f32_16x16x32_bf16(af[i], bfr[j], acc[i][j], 0, 0, 0);
  }

  // epilogue: D row = quad*4+r, col = lane&15
  #pragma unroll
  for (int mi = 0; mi < 4; ++mi) {
    #pragma unroll
    for (int ni = 0; ni < 4; ++ni) {
      #pragma unroll
      for (int r = 0; r < 4; ++r) {
        const int gm = m0 + wm + mi * 16 + quad * 4 + r;
        const int gn = n0 + wn + ni * 16 + lrow;
        const float val = acc[mi][ni][r];
        if (EPI == EPI_F32) {
          aux.c_f32[(long long)zC * aux.strideCz + (long long)gm * aux.ldc + gn] = val;
        } else if (EPI == EPI_VT) {
          const int b = gm >> 11, s = gm & (S_ - 1);
          const int h = gn >> 8, d = gn & (HD_ - 1);
          aux.c_bf16[((long long)(b * NH_ + h) * HD_ + d) * S_ + s] = f32_to_bf16(val);
        } else if (EPI == EPI_PV_O) {
          const int b = zC >> 2, h = zC & (NH_ - 1);
          aux.c_bf16[((long long)(b * S_ + gm)) * HID_ + h * HD_ + gn] = f32_to_bf16(val);
        } else if (EPI == EPI_WO) {
          const long long idx = (long long)gm * HID_ + gn;
          aux.out2[idx] = val + aux.add_src[idx];
        } else if (EPI == EPI_DOWN) {
          const long long idx = (long long)gm * HID_ + gn;
          aux.out2[idx] += val;
        }
      }
    }
  }
}

// ---- old dual-B GEMM, kept ONLY for the small-workspace fallback path ----
#define EPI2_GU 1   // out0 = bf16(silu(g)*u*rw[token][zb]), ldc=IM_

template<int EPI2>
__global__ __launch_bounds__(256, 2) void gemm_dual_k(
    const unsigned short* __restrict__ A,      // [M_][HID_]
    const unsigned short* __restrict__ B0b,    // B0 [*][HID_]
    const unsigned short* __restrict__ B1b,    // B1 [*][HID_]
    int zb,
    unsigned short* __restrict__ out0, unsigned short* __restrict__ out1,
    const float* __restrict__ rw)
{
  __shared__ unsigned short As[2][128 * 32];
  __shared__ unsigned short B0s[2][128 * 32];
  __shared__ unsigned short B1s[2][128 * 32];

  const int t = threadIdx.x;
  int bx, by;
  swizzle_xy(bx, by);
  const int m0 = by * 128, n0 = bx * 128;

  const int lane = t & 63, wave = t >> 6;
  const int wm = (wave >> 1) * 64, wn = (wave & 1) * 64;
  const int lrow = lane & 15, quad = lane >> 4;

  f32x4 acc0[4][4] = {}, acc1[4][4] = {};

  const int srow = lane >> 2;
  const int sko  = (lane & 3) * 8;
  const unsigned short* aRow0 = A   + (long long)(m0 + wave * 16       + srow) * HID_ + sko;
  const unsigned short* aRow1 = A   + (long long)(m0 + (wave + 4) * 16 + srow) * HID_ + sko;
  const unsigned short* gRow0 = B0b + (long long)(n0 + wave * 16       + srow) * HID_ + sko;
  const unsigned short* gRow1 = B0b + (long long)(n0 + (wave + 4) * 16 + srow) * HID_ + sko;
  const unsigned short* uRow0 = B1b + (long long)(n0 + wave * 16       + srow) * HID_ + sko;
  const unsigned short* uRow1 = B1b + (long long)(n0 + (wave + 4) * 16 + srow) * HID_ + sko;
  const int dst0 = (wave * 16) * 32, dst1 = ((wave + 4) * 16) * 32;

  gload16(aRow0, &As[0][dst0]);
  gload16(aRow1, &As[0][dst1]);
  gload16(gRow0, &B0s[0][dst0]);
  gload16(gRow1, &B0s[0][dst1]);
  gload16(uRow0, &B1s[0][dst0]);
  gload16(uRow1, &B1s[0][dst1]);

  int cur = 0;
  for (int kk = 0; kk < HID_; kk += 32, cur ^= 1) {
    __syncthreads();
    if (kk + 32 < HID_) {
      const int nxt = cur ^ 1, k2 = kk + 32;
      gload16(aRow0 + k2, &As[nxt][dst0]);
      gload16(aRow1 + k2, &As[nxt][dst1]);
      gload16(gRow0 + k2, &B0s[nxt][dst0]);
      gload16(gRow1 + k2, &B0s[nxt][dst1]);
      gload16(uRow0 + k2, &B1s[nxt][dst0]);
      gload16(uRow1 + k2, &B1s[nxt][dst1]);
    }
    bf16x8 af[4], b0[4], b1[4];
    #pragma unroll
    for (int i = 0; i < 4; ++i) {
      af[i] = *reinterpret_cast<const bf16x8*>(&As[cur][(wm + i * 16 + lrow) * 32 + quad * 8]);
      b0[i] = *reinterpret_cast<const bf16x8*>(&B0s[cur][(wn + i * 16 + lrow) * 32 + quad * 8]);
      b1[i] = *reinterpret_cast<const bf16x8*>(&B1s[cur][(wn + i * 16 + lrow) * 32 + quad * 8]);
    }
    #pragma unroll
    for (int i = 0; i < 4; ++i)
      #pragma unroll
      for (int j = 0; j < 4; ++j) {
        acc0[i][j] = __builtin_amdgcn_mfma_f32_16x16x32_bf16(af[i], b0[j], acc0[i][j], 0, 0, 0);
        acc1[i][j] = __builtin_amdgcn_mfma_f32_16x16x32_bf16(af[i], b1[j], acc1[i][j], 0, 0, 0);
      }
  }

  #pragma unroll
  for (int mi = 0; mi < 4; ++mi)
    #pragma unroll
    for (int r = 0; r < 4; ++r) {
      const int gm = m0 + wm + mi * 16 + quad * 4 + r;
      const float rwv = rw[(long long)gm * E_ + zb];
      #pragma unroll
      for (int ni = 0; ni < 4; ++ni) {
        const int gn = n0 + wn + ni * 16 + lrow;
        const float v0 = acc0[mi][ni][r];
        const float v1 = acc1[mi][ni][r];
        const float sg = v0 / (1.f + __expf(-v0));      // silu(gate)
        out0[(long long)gm * IM_ + gn] = f32_to_bf16(sg * v1 * rwv);
      }
    }
}

// =============== v3 pipelined GEMM: max-distance counted vmcnt ==============
// BM=256 x BN=128, BK=64, 512 threads = 8 waves (4M x 2N). 16 MFMA per phase.
// All staging via global_load_lds with pre-swizzled global source + swizzled
// ds_read (validated rounds 1-2: SQ_LDS_BANK_CONFLICT == 0).
//
// DUAL (A[2] 64K, B0[2] 32K, B1[2] 32K = 128 KiB), 4 phases/tile:
//   ph0: rd A.k0, B1.k0 | stage B0(T+1)      | vmcnt(8) | BAR lgk0 MFMA acc1 BAR
//   ph1: rd B0.k0       |                    |          | BAR lgk0 MFMA acc0 BAR
//   ph2: rd A.k1, B1.k1 |                    |          | BAR lgk0 MFMA acc1 BAR
//   ph3: rd B0.k1       | stage A(T+2),B1(T+2)| vmcnt(8)| BAR lgk0 MFMA acc0 BAR
//   Every waited load was issued exactly 4 phases earlier (T4 discipline).
// SINGLE (+optional PAIRK K-concat): A[2] 64K, B[3] 48K = 112 KiB, 2 ph/tile:
//   ph0: rd A.k0, A.k1, B.k0 | stage B(T+2) | BAR lgk0 MFMA BAR
//   ph1: rd B.k1             | stage A(T+2) | vmcnt(6) | BAR lgk0 MFMA BAR
//   Distances: B 4 phases, A 2 phases.
// Tail (last 2 tiles) peels to vmcnt(2)/vmcnt(0) per exact queue enumeration.
#define EPI5_GU   0   // out0 = bf16(silu(acc0)*acc1*rw[token][expert]), ld IM_
#define EPI5_QK   1   // out0/out1 = bf16(elu(acc)+1), ld HID_
#define EPI5_DOWN 2   // o_f32 += acc0, ld HID_
#define EPI5_WO   3   // o_f32 = acc0 + add_src, ld HID_
template<bool DUAL, int EPI, int KTOT, int KROW, bool PAIRK>
__global__ __launch_bounds__(512, 2) void gemm5_k(
    const unsigned short* A0, const unsigned short* A1,
    const unsigned short* B0b, const unsigned short* B1b,
    const float* __restrict__ rw, int expert,
    unsigned short* out0, unsigned short* out1,
    float* o_f32, const float* add_src)
{
  constexpr int NT  = KTOT / 64;
  constexpr int NT2 = NT / 2;
  __shared__ unsigned short smem[DUAL ? 65536 : 57344];

  const int t = threadIdx.x, wave = t >> 6, lane = t & 63;
  const int lrow = lane & 15, quad = lane >> 4;
  const int wrow0 = (wave >> 1) * 64;   // 0..192
  const int wcol0 = (wave & 1) * 64;    // 0/64

  int bx, by;
  swizzle_xy(bx, by);
  const int m0 = by * 256, n0 = bx * 128;

  const int r8  = lane >> 3;
  const int csw = ((lane & 7) ^ r8) << 4;   // pre-swizzled global byte col

  auto unit = [&](const unsigned short* mat, int grow0, int ktl, int ldsElem) {
    #pragma unroll
    for (int i = 0; i < 2; ++i) {
      const char* src = (const char*)(mat + (size_t)(grow0 + wave * 16 + i * 8 + r8) * KROW)
                        + (size_t)ktl * 128 + csw;
      gload16((const unsigned short*)src, &smem[ldsElem + wave * 1024 + i * 512]);
    }
  };
  auto stageA = [&](int kt) {           // 4 loads/thread -> A[kt&1]
    const unsigned short* m = A0; int ktl = kt;
    if constexpr (PAIRK) { if (kt >= NT2) { m = A1; ktl = kt - NT2; } }
    const int buf = kt & 1;
    unit(m, m0,       ktl, buf * 16384);
    unit(m, m0 + 128, ktl, buf * 16384 + 8192);
  };
  auto stageB = [&](int kt, int which, int bufB) {  // 2 loads/thread
    const unsigned short* m; int ktl = kt;
    if constexpr (DUAL) {
      m = which ? B1b : B0b;
    } else {
      m = B0b;
      if constexpr (PAIRK) { if (kt >= NT2) { m = B1b; ktl = kt - NT2; } }
    }
    unit(m, n0, ktl, 32768 + (DUAL ? which * 16384 : 0) + bufB * 8192);
  };

  const int xr = (lane & 7) << 4;
  auto readA_ = [&](bf16x8* o, int buf, int ks) {
    const char* base = (const char*)smem + buf * 32768 + (wrow0 >> 7) * 16384;
    const int rl0 = wrow0 & 127;
    #pragma unroll
    for (int mi = 0; mi < 4; ++mi)
      o[mi] = *(const bf16x8*)(base + (rl0 + mi * 16 + lrow) * 128 + ((ks * 64 + quad * 16) ^ xr));
  };
  auto readB_ = [&](bf16x8* o, int baseByte, int ks) {
    const char* base = (const char*)smem + baseByte;
    #pragma unroll
    for (int nj = 0; nj < 4; ++nj)
      o[nj] = *(const bf16x8*)(base + (wcol0 + nj * 16 + lrow) * 128 + ((ks * 64 + quad * 16) ^ xr));
  };

  f32x4 acc0[4][4] = {};
  f32x4 acc1[4][4] = {};
  auto mm = [&](f32x4 (&ac)[4][4], const bf16x8* aF, const bf16x8* bF) {
    #pragma unroll
    for (int mi = 0; mi < 4; ++mi)
      #pragma unroll
      for (int nj = 0; nj < 4; ++nj)
        ac[mi][nj] = __builtin_amdgcn_mfma_f32_16x16x32_bf16(aF[mi], bF[nj], ac[mi][nj], 0, 0, 0);
  };

  bf16x8 a0[4], a1[4], bF[4];

  if constexpr (DUAL) {
    // prologue queue: [A(0)4, B1(0)2, B0(0)2, A(1)4, B1(1)2] = 14
    stageA(0); stageB(0, 1, 0); stageB(0, 0, 0); stageA(1); stageB(1, 1, 1);
    vwait<8>();                     // drain A(0), B1(0)
    __builtin_amdgcn_s_barrier();

    for (int T = 0; T < NT; ++T) {
      const int c = T & 1;
      const int bB1 = 65536 + 32768 + c * 16384;   // B1[c] byte base
      const int bB0 = 65536 + c * 16384;           // B0[c] byte base
      // ---- ph0: acc1 += A.k0 * B1.k0 ----
      readA_(a0, c, 0);
      readB_(bF, bB1, 0);
      if (T + 1 < NT) stageB(T + 1, 0, (T + 1) & 1);
      if (T < NT - 1) vwait<8>(); else vwait<0>();   // W2: B0(T) landed
      __builtin_amdgcn_s_barrier();
      lgk0();
      __builtin_amdgcn_s_setprio(1); mm(acc1, a0, bF); __builtin_amdgcn_s_setprio(0);
      __builtin_amdgcn_s_barrier();
      // ---- ph1: acc0 += A.k0 * B0.k0 ----
      readB_(bF, bB0, 0);
      __builtin_amdgcn_s_barrier();
      lgk0();
      __builtin_amdgcn_s_setprio(1); mm(acc0, a0, bF); __builtin_amdgcn_s_setprio(0);
      __builtin_amdgcn_s_barrier();
      // ---- ph2: acc1 += A.k1 * B1.k1 ----
      readA_(a1, c, 1);
      readB_(bF, bB1, 1);
      __builtin_amdgcn_s_barrier();
      lgk0();
      __builtin_amdgcn_s_setprio(1); mm(acc1, a1, bF); __builtin_amdgcn_s_setprio(0);
      __builtin_amdgcn_s_barrier();
      // ---- ph3: acc0 += A.k1 * B0.k1 ----
      readB_(bF, bB0, 1);
      if (T + 2 < NT) { stageA(T + 2); stageB(T + 2, 1, c); }
      if (T < NT - 2) vwait<8>();                    // W1: A(T+1),B1(T+1)
      else if (T == NT - 2) vwait<2>();
      __builtin_amdgcn_s_barrier();
      lgk0();
      __builtin_amdgcn_s_setprio(1); mm(acc0, a1, bF); __builtin_amdgcn_s_setprio(0);
      __builtin_amdgcn_s_barrier();
    }
  } else {
    // prologue queue: [B(0)2, A(0)4, B(1)2, A(1)4] = 12
    stageB(0, 0, 0); stageA(0); stageB(1, 0, 1); stageA(1);
    vwait<6>();                     // drain B(0), A(0)
    __builtin_amdgcn_s_barrier();

    int b = 0;
    for (int T = 0; T < NT; ++T) {
      const int c = T & 1;
      const int bB = 65536 + b * 16384;
      int bn = b + 2; if (bn >= 3) bn -= 3;
      // ---- ph0 ----
      readA_(a0, c, 0);
      readA_(a1, c, 1);
      readB_(bF, bB, 0);
      if (T + 2 < NT) stageB(T + 2, 0, bn);
      __builtin_amdgcn_s_barrier();
      lgk0();
      __builtin_amdgcn_s_setprio(1); mm(acc0, a0, bF); __builtin_amdgcn_s_setprio(0);
      __builtin_amdgcn_s_barrier();
      // ---- ph1 ----
      readB_(bF, bB, 1);
      if (T + 2 < NT) stageA(T + 2);
      if (T < NT - 2) vwait<6>();                    // W: B(T+1), A(T+1)
      else if (T == NT - 2) vwait<0>();
      __builtin_amdgcn_s_barrier();
      lgk0();
      __builtin_amdgcn_s_setprio(1); mm(acc0, a1, bF); __builtin_amdgcn_s_setprio(0);
      __builtin_amdgcn_s_barrier();
      if (++b == 3) b = 0;
    }
  }

  // epilogue: D row = quad*4+r, col = lane&15
  #pragma unroll
  for (int mi = 0; mi < 4; ++mi) {
    #pragma unroll
    for (int r = 0; r < 4; ++r) {
      const int gm = m0 + wrow0 + mi * 16 + quad * 4 + r;
      float rwv = 0.f;
      if (EPI == EPI5_GU) rwv = rw[(size_t)gm * E_ + expert];
      #pragma unroll
      for (int nj = 0; nj < 4; ++nj) {
        const int gn = n0 + wcol0 + nj * 16 + lrow;
        const float v0 = acc0[mi][nj][r];
        if (EPI == EPI5_GU) {
          const float v1 = acc1[mi][nj][r];
          const float sg = v0 / (1.f + __expf(-v0));
          out0[(size_t)gm * IM_ + gn] = f32_to_bf16(sg * v1 * rwv);
        } else if (EPI == EPI5_QK) {
          const float v1 = acc1[mi][nj][r];
          out0[(size_t)gm * HID_ + gn] = f32_to_bf16(v0 > 0.f ? v0 + 1.f : __expf(v0));
          out1[(size_t)gm * HID_ + gn] = f32_to_bf16(v1 > 0.f ? v1 + 1.f : __expf(v1));
        } else if (EPI == EPI5_DOWN) {
          o_f32[(size_t)gm * HID_ + gn] += v0;
        } else {  // EPI5_WO
          const size_t idx = (size_t)gm * HID_ + gn;
          o_f32[idx] = v0 + add_src[idx];
        }
      }
    }
  }
}

// fp32 [R][C] -> bf16 [C][R]; z selects among 4 sources, dst stride R*C
__global__ void transpose_cast4_k(const float* s0, const float* s1,
                                  const float* s2, const float* s3,
                                  unsigned short* __restrict__ out, int R, int C)
{
  __shared__ float tile[32][33];
  const int z = blockIdx.z;
  const float* in = (z == 0) ? s0 : (z == 1) ? s1 : (z == 2) ? s2 : s3;
  unsigned short* o = out + (long long)z * R * C;
  const int c0 = blockIdx.x * 32, r0 = blockIdx.y * 32;
  const int tx = threadIdx.x, ty = threadIdx.y;
  #pragma unroll
  for (int i = 0; i < 32; i += 8)
    tile[ty + i][tx] = in[(long long)(r0 + ty + i) * C + c0 + tx];
  __syncthreads();
  #pragma unroll
  for (int i = 0; i < 32; i += 8)
    o[(long long)(c0 + ty + i) * R + r0 + tx] = f32_to_bf16(tile[tx][ty + i]);
}

// fp32 [R][C] -> bf16 [C][R]; z<4: srcA/dstA expert z; z>=4: srcB/dstB
__global__ void transpose_cast2x4_k(const float* __restrict__ sA,
                                    const float* __restrict__ sB,
                                    unsigned short* __restrict__ dA,
                                    unsigned short* __restrict__ dB,
                                    int R, int C)
{
  __shared__ float tile[32][33];
  const int z = blockIdx.z;
  const long long eo = (long long)(z & 3) * R * C;
  const float* in = ((z < 4) ? sA : sB) + eo;
  unsigned short* o = ((z < 4) ? dA : dB) + eo;
  const int c0 = blockIdx.x * 32, r0 = blockIdx.y * 32;
  const int tx = threadIdx.x, ty = threadIdx.y;
  #pragma unroll
  for (int i = 0; i < 32; i += 8)
    tile[ty + i][tx] = in[(long long)(r0 + ty + i) * C + c0 + tx];
  __syncthreads();
  #pragma unroll
  for (int i = 0; i < 32; i += 8)
    o[(long long)(c0 + ty + i) * R + r0 + tx] = f32_to_bf16(tile[tx][ty + i]);
}

// fp32 [R][C] -> bf16 [C][R], batched over z (single base, stride R*C)
__global__ void transpose_cast_k(const float* __restrict__ in,
                                 unsigned short* __restrict__ out, int R, int C)
{
  __shared__ float tile[32][33];
  const long long bo = (long long)blockIdx.z * R * C;
  const int c0 = blockIdx.x * 32, r0 = blockIdx.y * 32;
  const int tx = threadIdx.x, ty = threadIdx.y;
  #pragma unroll
  for (int i = 0; i < 32; i += 8)
    tile[ty + i][tx] = in[bo + (long long)(r0 + ty + i) * C + c0 + tx];
  __syncthreads();
  #pragma unroll
  for (int i = 0; i < 32; i += 8)
    out[bo + (long long)(c0 + ty + i) * R + r0 + tx] = f32_to_bf16(tile[tx][ty + i]);
}

// rmsnorm row (HID=1024) + weight + bf16 cast; one block per token
__global__ __launch_bounds__(256) void rmsnorm_cast_k(
    const float* __restrict__ x, const float* __restrict__ w,
    unsigned short* __restrict__ out)
{
  __shared__ float red[4];
  const int row = blockIdx.x, t = threadIdx.x;
  const float4 v = reinterpret_cast<const float4*>(x + (long long)row * HID_)[t];
  float ss = v.x * v.x + v.y * v.y + v.z * v.z + v.w * v.w;
  #pragma unroll
  for (int off = 32; off > 0; off >>= 1) ss += __shfl_down(ss, off, 64);
  if ((t & 63) == 0) red[t >> 6] = ss;
  __syncthreads();
  ss = red[0] + red[1] + red[2] + red[3];
  const float inv = rsqrtf(ss * (1.0f / HID_) + 1e-6f);
  const float4 wv = reinterpret_cast<const float4*>(w)[t];
  ushort4 o;
  o.x = f32_to_bf16(v.x * inv * wv.x);
  o.y = f32_to_bf16(v.y * inv * wv.y);
  o.z = f32_to_bf16(v.z * inv * wv.z);
  o.w = f32_to_bf16(v.w * inv * wv.w);
  reinterpret_cast<ushort4*>(out + (long long)row * HID_)[t] = o;
}

// softmax over a 2048-wide fp32 row; writes P bf16 IN PLACE over the row
__global__ __launch_bounds__(256) void softmax_rows_k(float* __restrict__ scores)
{
  __shared__ float red[4];
  const long long rbase = ((long long)blockIdx.y * S_ + blockIdx.x) * S_;
  float* row = scores + rbase;
  const int t = threadIdx.x;
  float v[8];
  #pragma unroll
  for (int i = 0; i < 8; ++i) v[i] = row[t + i * 256];
  float m = v[0];
  #pragma unroll
  for (int i = 1; i < 8; ++i) m = fmaxf(m, v[i]);
  #pragma unroll
  for (int off = 32; off > 0; off >>= 1) m = fmaxf(m, __shfl_down(m, off, 64));
  if ((t & 63) == 0) red[t >> 6] = m;
  __syncthreads();
  m = fmaxf(fmaxf(red[0], red[1]), fmaxf(red[2], red[3]));
  __syncthreads();
  float s = 0.f;
  #pragma unroll
  for (int i = 0; i < 8; ++i) { v[i] = __expf(v[i] - m); s += v[i]; }
  #pragma unroll
  for (int off = 32; off > 0; off >>= 1) s += __shfl_down(s, off, 64);
  if ((t & 63) == 0) red[t >> 6] = s;
  __syncthreads();
  const float inv = 1.0f / (red[0] + red[1] + red[2] + red[3]);
  unsigned short* prow = reinterpret_cast<unsigned short*>(scores) + rbase * 2;
  #pragma unroll
  for (int i = 0; i < 8; ++i) prow[t + i * 256] = f32_to_bf16(v[i] * inv);
}

// router: fp32 rms(h1)*ln2w @ router_w + b, softmax over E=4. One wave/token.
__global__ __launch_bounds__(256) void router_k(
    const float* __restrict__ h1, const float* __restrict__ ln2w,
    const float* __restrict__ rwgt, const float* __restrict__ rbias,
    float* __restrict__ rw)
{
  const int wv = threadIdx.x >> 6, lane = threadIdx.x & 63;
  const long long m = (long long)blockIdx.x * 4 + wv;
  const float* xr = h1 + m * HID_;
  float xv[16];
  float ss = 0.f;
  #pragma unroll
  for (int i = 0; i < 16; ++i) { xv[i] = xr[lane + i * 64]; ss += xv[i] * xv[i]; }
  #pragma unroll
  for (int off = 32; off > 0; off >>= 1) ss += __shfl_down(ss, off, 64);
  ss = __shfl(ss, 0, 64);
  const float inv = rsqrtf(ss * (1.0f / HID_) + 1e-6f);
  float l0 = 0, l1 = 0, l2 = 0, l3 = 0;
  #pragma unroll
  for (int i = 0; i < 16; ++i) {
    const int k = lane + i * 64;
    const float xn = xv[i] * inv * ln2w[k];
    const float4 wr = reinterpret_cast<const float4*>(rwgt)[k];
    l0 += xn * wr.x; l1 += xn * wr.y; l2 += xn * wr.z; l3 += xn * wr.w;
  }
  #pragma unroll
  for (int off = 32; off > 0; off >>= 1) {
    l0 += __shfl_down(l0, off, 64);
    l1 += __shfl_down(l1, off, 64);
    l2 += __shfl_down(l2, off, 64);
    l3 += __shfl_down(l3, off, 64);
  }
  if (lane == 0) {
    l0 += rbias[0]; l1 += rbias[1]; l2 += rbias[2]; l3 += rbias[3];
    const float mx = fmaxf(fmaxf(l0, l1), fmaxf(l2, l3));
    const float e0 = __expf(l0 - mx), e1 = __expf(l1 - mx);
    const float e2 = __expf(l2 - mx), e3 = __expf(l3 - mx);
    const float is = 1.0f / (e0 + e1 + e2 + e3);
    reinterpret_cast<float4*>(rw)[m] = make_float4(e0 * is, e1 * is, e2 * is, e3 * is);
  }
}

// balance loss: single block, deterministic
__global__ __launch_bounds__(256) void balance_k(const float* __restrict__ rw,
                                                 float* __restrict__ out_scalar)
{
  __shared__ float red[4];
  float acc = 0.f;
  for (int it = threadIdx.x; it < S_ * E_; it += 256) {
    const int s = it >> 2, e = it & 3;
    float mr = 0.f;
    #pragma unroll
    for (int b = 0; b < B_; ++b) mr += rw[((long long)b * S_ + s) * E_ + e];
    mr *= (1.0f / B_);
    const float d = mr - 1.0f / E_;
    acc += d * d;
  }
  #pragma unroll
  for (int off = 32; off > 0; off >>= 1) acc += __shfl_down(acc, off, 64);
  if ((threadIdx.x & 63) == 0) red[threadIdx.x >> 6] = acc;
  __syncthreads();
  if (threadIdx.x == 0)
    out_scalar[0] = (red[0] + red[1] + red[2] + red[3]) * (0.01f / (S_ * E_));
}

extern "C" void kernel_launch(void* const* d_in, const int* in_sizes, int n_in,
                              void* d_out, int out_size, void* d_ws, size_t ws_size,
                              hipStream_t stream)
{
  const float* hidden   = (const float*)d_in[0];
  const float* ln1w     = (const float*)d_in[1];
  const float* wq       = (const float*)d_in[2];
  const float* wk       = (const float*)d_in[3];
  const float* wv       = (const float*)d_in[4];
  const float* wo       = (const float*)d_in[5];
  const float* ln2w     = (const float*)d_in[6];
  const float* router_w = (const float*)d_in[7];
  const float* router_b = (const float*)d_in[8];
  const float* gate_w   = (const float*)d_in[9];
  const float* up_w     = (const float*)d_in[10];
  const float* down_w   = (const float*)d_in[11];
  float* out = (float*)d_out;   // h1 lives here; MoE accumulates in place

  char* ws = (char*)d_ws;
  size_t off = 0;
  auto carve = [&](size_t bytes) {
    off = (off + 255) & ~(size_t)255;
    char* p = ws + off;
    off += bytes;
    return p;
  };
  unsigned short* wqT   = (unsigned short*)carve((size_t)HID_ * HID_ * 2);  // 2 MiB
  unsigned short* wkT   = (unsigned short*)carve((size_t)HID_ * HID_ * 2);
  unsigned short* wvT   = (unsigned short*)carve((size_t)HID_ * HID_ * 2);
  unsigned short* woT   = (unsigned short*)carve((size_t)HID_ * HID_ * 2);
  unsigned short* x_bf  = (unsigned short*)carve((size_t)M_ * HID_ * 2);    // 16 MiB, reused as o_bf
  unsigned short* qb    = (unsigned short*)carve((size_t)M_ * HID_ * 2);    // 16 MiB, reused as x2_bf
  unsigned short* kb    = (unsigned short*)carve((size_t)M_ * HID_ * 2);    // 16 MiB \ gu0 (32 MiB)
  unsigned short* vT    = (unsigned short*)carve((size_t)M_ * HID_ * 2);    // 16 MiB /
  float*          rwbuf = (float*)carve((size_t)M_ * E_ * 4);               // 128 KiB
  char*           ubase = carve((size_t)NHG_ * S_ * S_ * 4);                // 64 MiB union
  float*          scores = (float*)ubase;
  unsigned short* gateT = (unsigned short*)(ubase);                          // 16 MiB
  unsigned short* upT   = (unsigned short*)(ubase + (size_t)16 * 1024 * 1024);
  unsigned short* downT = (unsigned short*)(ubase + (size_t)32 * 1024 * 1024);
  unsigned short* o_bf  = x_bf;
  unsigned short* x2_bf = qb;
  unsigned short* gu0   = kb;   // spans kb+vT = 32 MiB
  // second 32 MiB buffer: gu of the odd expert (down pair reads both)
  unsigned short* gu1   = (unsigned short*)carve((size_t)M_ * IM_ * 2);     // +32 MiB
  const bool paired = (ws_size >= off);

  const dim3 blk256(256), blk512(512), blkT(32, 8);

  // 1) attention weights -> bf16 B^T (one dispatch, z=4)
  transpose_cast4_k<<<dim3(32, 32, 4), blkT, 0, stream>>>(wq, wk, wv, wo, wqT, HID_, HID_);

  // 2) x = bf16(rms(hidden, ln1_w))
  rmsnorm_cast_k<<<M_, blk256, 0, stream>>>(hidden, ln1w, x_bf);

  // 3) Q+K fused (dual v3, shared A staging, elu+1 epilogue); V transposed
  gemm5_k<true, EPI5_QK, 1024, 1024, false><<<dim3(8, 32, 1), blk512, 0, stream>>>(
      x_bf, nullptr, wqT, wkT, nullptr, 0, qb, kb, nullptr, nullptr);
  {
    EpiAux a{}; a.c_bf16 = vT;
    gemm_bf16k<EPI_VT><<<dim3(8, 64, 1), blk256, 0, stream>>>(
        x_bf, HID_, 0, 0, 0, wvT, HID_, 0, 0, 0, 0, 0, 0, HID_, a);
  }

  // 4) attention, NHG_=4 heads per group; scores slab reused per group
  for (int grp = 0; grp < 16 / NHG_; ++grp) {
    EpiAux as{}; as.c_f32 = scores; as.ldc = S_; as.strideCz = (long long)S_ * S_;
    gemm_bf16k<EPI_F32><<<dim3(16, 16, NHG_), blk256, 0, stream>>>(
        qb, HID_, (long long)S_ * HID_, HD_, grp * NHG_,
        kb, HID_, (long long)S_ * HID_, HD_, grp * NHG_,
        2, 3, 0, HD_, as);
    softmax_rows_k<<<dim3(S_, NHG_, 1), blk256, 0, stream>>>(scores);
    EpiAux ap{}; ap.c_bf16 = o_bf;
    gemm_bf16k<EPI_PV_O><<<dim3(2, 16, NHG_), blk256, 0, stream>>>(
        (const unsigned short*)scores, 2 * S_, (long long)S_ * 2 * S_, 0, 0,
        vT, S_, (long long)HD_ * S_, 0, grp * NHG_,
        0, 0, grp * NHG_, S_, ap);
  }

  // 5) MoE weights -> bf16 B^T into the now-dead scores slab
  transpose_cast2x4_k<<<dim3(64, 32, 8), blkT, 0, stream>>>(
      gate_w, up_w, gateT, upT, HID_, IM_);
  transpose_cast_k<<<dim3(32, 64, E_), blkT, 0, stream>>>(down_w, downT, IM_, HID_);

  // 6) h1 = hidden + O @ wo (v3 single pipeline), written straight into d_out
  gemm5_k<false, EPI5_WO, 1024, 1024, false><<<dim3(8, 32, 1), blk512, 0, stream>>>(
      o_bf, nullptr, woT, nullptr, nullptr, 0, nullptr, nullptr, out, hidden);

  // 7) x2 = bf16(rms(h1, ln2_w)); router (fp32); balance loss scalar
  rmsnorm_cast_k<<<M_, blk256, 0, stream>>>(out, ln2w, x2_bf);
  router_k<<<M_ / 4, blk256, 0, stream>>>(out, ln2w, router_w, router_b, rwbuf);
  balance_k<<<1, blk256, 0, stream>>>(rwbuf, out + (size_t)M_ * HID_);

  // 8) dense MoE: fused dual-B GU (silu*u*rw folded) per expert on the v3
  //    kernel; expert-paired down via PAIRK K-concat (K=4096).
  const size_t wsz = (size_t)IM_ * HID_;
  if (paired) {
    for (int p = 0; p < 2; ++p) {
      const int e0 = 2 * p, e1 = e0 + 1;
      gemm5_k<true, EPI5_GU, 1024, 1024, false><<<dim3(16, 32, 1), blk512, 0, stream>>>(
          x2_bf, nullptr, gateT + (size_t)e0 * wsz, upT + (size_t)e0 * wsz,
          rwbuf, e0, gu0, nullptr, nullptr, nullptr);
      gemm5_k<true, EPI5_GU, 1024, 1024, false><<<dim3(16, 32, 1), blk512, 0, stream>>>(
          x2_bf, nullptr, gateT + (size_t)e1 * wsz, upT + (size_t)e1 * wsz,
          rwbuf, e1, gu1, nullptr, nullptr, nullptr);
      gemm5_k<false, EPI5_DOWN, 4096, 2048, true><<<dim3(8, 32, 1), blk512, 0, stream>>>(
          gu0, gu1, downT + (size_t)e0 * wsz, downT + (size_t)e1 * wsz,
          nullptr, 0, nullptr, nullptr, out, nullptr);
    }
  } else {
    for (int i = 0; i < E_; ++i) {
      gemm_dual_k<EPI2_GU><<<dim3(16, 64, 1), blk256, 0, stream>>>(
          x2_bf, gateT + (size_t)i * wsz, upT + (size_t)i * wsz, i, gu0, nullptr, rwbuf);
      EpiAux ad{}; ad.out2 = out;
      gemm_bf16k<EPI_DOWN><<<dim3(8, 64, 1), blk256, 0, stream>>>(
          gu0, IM_, 0, 0, 0, downT + (size_t)i * wsz, IM_, 0, 0, 0,
          0, 0, 0, IM_, ad);
    }
  }
}

// Round 4
// 1074.393 us; speedup vs baseline: 1.0072x; 1.0072x over previous
//
#include <hip/hip_runtime.h>
#include <cstdint>
#include <cstddef>

// Problem constants (B,S,HID,NH,IM,E fixed by the reference)
#define B_    4
#define S_    2048
#define HID_  1024
#define NH_   4
#define HD_   256     // HID/NH
#define IM_   2048
#define E_    4
#define M_    8192    // B_*S_ tokens
#define NHG_  4       // heads per attention group

typedef __bf16 bf16x8 __attribute__((ext_vector_type(8)));
typedef float  f32x4  __attribute__((ext_vector_type(4)));

__device__ __forceinline__ unsigned short f32_to_bf16(float f) {
  unsigned int u = __float_as_uint(f);
  u += 0x7fffu + ((u >> 16) & 1u);   // round-to-nearest-even
  return (unsigned short)(u >> 16);
}

// async 16B global->LDS DMA (global_load_lds_dwordx4). LDS dest is
// wave-uniform base + lane*16 -> LDS layout contiguous in lane order.
__device__ __forceinline__ void gload16(const unsigned short* g, unsigned short* l) {
  __builtin_amdgcn_global_load_lds(
      (const __attribute__((address_space(1))) void*)g,
      (__attribute__((address_space(3))) void*)l, 16, 0, 0);
}

template<int N> __device__ __forceinline__ void vwait() {
  if constexpr (N == 0)      asm volatile("s_waitcnt vmcnt(0)" ::: "memory");
  else if constexpr (N == 2) asm volatile("s_waitcnt vmcnt(2)" ::: "memory");
  else if constexpr (N == 4) asm volatile("s_waitcnt vmcnt(4)" ::: "memory");
  else if constexpr (N == 6) asm volatile("s_waitcnt vmcnt(6)" ::: "memory");
  else                       asm volatile("s_waitcnt vmcnt(8)" ::: "memory");
}
__device__ __forceinline__ void lgk0() {
  asm volatile("s_waitcnt lgkmcnt(0)" ::: "memory");
}

// XCD-aware swizzle: contiguous y-bands per XCD.
__device__ __forceinline__ void swizzle_xy(int& bx, int& by) {
  const int gx = gridDim.x, gy = gridDim.y;
  const int flat = blockIdx.x + blockIdx.y * gx;
  const int xcd = flat & 7, i = flat >> 3;
  const int rpx = gy >> 3;          // y-rows per XCD
  bx = i % gx;
  by = xcd * rpx + i / gx;
}

// ---------------- epilogue variants (generic single-B GEMM) ----------------
#define EPI_F32      0   // C fp32 (attention scores), batched via strideCz
#define EPI_VT       2   // write V^T [b][h][d][s] bf16
#define EPI_PV_O     3   // write attn O into [token][h*HD+n] bf16
#define EPI_WO       4   // out2 = add_src + acc  (fallback)
#define EPI_DOWN     5   // out2 += acc  (fallback path)

struct EpiAux {
  float* c_f32;
  unsigned short* c_bf16;
  const float* add_src;       // hidden (WO)
  float* out2;                // d_out (WO/DOWN)
  long long strideCz;
  int ldc;
};

// Generic batched GEMM: C[z] = A[z] (MxK, row-major, lda) @ B[z]^T.
// 128x128 tile, BK=32, 4 waves x (4x4) 16x16x32 bf16 MFMA fragments.
// Double-buffered LDS, one-iteration-ahead async global_load_lds prefetch.
template<int EPI>
__global__ __launch_bounds__(256) void gemm_bf16k(
    const unsigned short* __restrict__ A, int lda, long long sAo, long long sAi, int zbA,
    const unsigned short* __restrict__ B, int ldb, long long sBo, long long sBi, int zbB,
    int zshift, int zmask, int zbC, int K, EpiAux aux)
{
  __shared__ unsigned short As[2][128 * 32];
  __shared__ unsigned short Bs[2][128 * 32];

  const int t = threadIdx.x;
  int bx, by;
  swizzle_xy(bx, by);
  const int m0 = by * 128, n0 = bx * 128;
  const int z  = blockIdx.z;
  const int zA = z + zbA, zB = z + zbB, zC = z + zbC;
  const unsigned short* Ab = A + (long long)(zA >> zshift) * sAo + (long long)(zA & zmask) * sAi;
  const unsigned short* Bb = B + (long long)(zB >> zshift) * sBo + (long long)(zB & zmask) * sBi;

  const int lane = t & 63, wave = t >> 6;
  const int wm = (wave >> 1) * 64, wn = (wave & 1) * 64;
  const int lrow = lane & 15, quad = lane >> 4;

  f32x4 acc[4][4] = {};

  const int srow = lane >> 2;         // 0..15
  const int sko  = (lane & 3) * 8;    // k-elem 0/8/16/24
  const unsigned short* aRow0 = Ab + (long long)(m0 + wave * 16       + srow) * lda + sko;
  const unsigned short* aRow1 = Ab + (long long)(m0 + (wave + 4) * 16 + srow) * lda + sko;
  const unsigned short* bRow0 = Bb + (long long)(n0 + wave * 16       + srow) * ldb + sko;
  const unsigned short* bRow1 = Bb + (long long)(n0 + (wave + 4) * 16 + srow) * ldb + sko;
  const int dst0 = (wave * 16) * 32, dst1 = ((wave + 4) * 16) * 32;

  gload16(aRow0, &As[0][dst0]);
  gload16(aRow1, &As[0][dst1]);
  gload16(bRow0, &Bs[0][dst0]);
  gload16(bRow1, &Bs[0][dst1]);

  int cur = 0;
  for (int kk = 0; kk < K; kk += 32, cur ^= 1) {
    __syncthreads();
    if (kk + 32 < K) {
      const int nxt = cur ^ 1, k2 = kk + 32;
      gload16(aRow0 + k2, &As[nxt][dst0]);
      gload16(aRow1 + k2, &As[nxt][dst1]);
      gload16(bRow0 + k2, &Bs[nxt][dst0]);
      gload16(bRow1 + k2, &Bs[nxt][dst1]);
    }
    bf16x8 af[4], bfr[4];
    #pragma unroll
    for (int i = 0; i < 4; ++i) {
      af[i]  = *reinterpret_cast<const bf16x8*>(&As[cur][(wm + i * 16 + lrow) * 32 + quad * 8]);
      bfr[i] = *reinterpret_cast<const bf16x8*>(&Bs[cur][(wn + i * 16 + lrow) * 32 + quad * 8]);
    }
    #pragma unroll
    for (int i = 0; i < 4; ++i)
      #pragma unroll
      for (int j = 0; j < 4; ++j)
        acc[i][j] = __builtin_amdgcn_mfma_f32_16x16x32_bf16(af[i], bfr[j], acc[i][j], 0, 0, 0);
  }

  // epilogue: D row = quad*4+r, col = lane&15
  #pragma unroll
  for (int mi = 0; mi < 4; ++mi) {
    #pragma unroll
    for (int ni = 0; ni < 4; ++ni) {
      #pragma unroll
      for (int r = 0; r < 4; ++r) {
        const int gm = m0 + wm + mi * 16 + quad * 4 + r;
        const int gn = n0 + wn + ni * 16 + lrow;
        const float val = acc[mi][ni][r];
        if (EPI == EPI_F32) {
          aux.c_f32[(long long)zC * aux.strideCz + (long long)gm * aux.ldc + gn] = val;
        } else if (EPI == EPI_VT) {
          const int b = gm >> 11, s = gm & (S_ - 1);
          const int h = gn >> 8, d = gn & (HD_ - 1);
          aux.c_bf16[((long long)(b * NH_ + h) * HD_ + d) * S_ + s] = f32_to_bf16(val);
        } else if (EPI == EPI_PV_O) {
          const int b = zC >> 2, h = zC & (NH_ - 1);
          aux.c_bf16[((long long)(b * S_ + gm)) * HID_ + h * HD_ + gn] = f32_to_bf16(val);
        } else if (EPI == EPI_WO) {
          const long long idx = (long long)gm * HID_ + gn;
          aux.out2[idx] = val + aux.add_src[idx];
        } else if (EPI == EPI_DOWN) {
          const long long idx = (long long)gm * HID_ + gn;
          aux.out2[idx] += val;
        }
      }
    }
  }
}

// ---- old dual-B GEMM, kept ONLY for the small-workspace fallback path ----
#define EPI2_GU 1   // out0 = bf16(silu(g)*u*rw[token][zb]), ldc=IM_

template<int EPI2>
__global__ __launch_bounds__(256, 2) void gemm_dual_k(
    const unsigned short* __restrict__ A,      // [M_][HID_]
    const unsigned short* __restrict__ B0b,    // B0 [*][HID_]
    const unsigned short* __restrict__ B1b,    // B1 [*][HID_]
    int zb,
    unsigned short* __restrict__ out0, unsigned short* __restrict__ out1,
    const float* __restrict__ rw)
{
  __shared__ unsigned short As[2][128 * 32];
  __shared__ unsigned short B0s[2][128 * 32];
  __shared__ unsigned short B1s[2][128 * 32];

  const int t = threadIdx.x;
  int bx, by;
  swizzle_xy(bx, by);
  const int m0 = by * 128, n0 = bx * 128;

  const int lane = t & 63, wave = t >> 6;
  const int wm = (wave >> 1) * 64, wn = (wave & 1) * 64;
  const int lrow = lane & 15, quad = lane >> 4;

  f32x4 acc0[4][4] = {}, acc1[4][4] = {};

  const int srow = lane >> 2;
  const int sko  = (lane & 3) * 8;
  const unsigned short* aRow0 = A   + (long long)(m0 + wave * 16       + srow) * HID_ + sko;
  const unsigned short* aRow1 = A   + (long long)(m0 + (wave + 4) * 16 + srow) * HID_ + sko;
  const unsigned short* gRow0 = B0b + (long long)(n0 + wave * 16       + srow) * HID_ + sko;
  const unsigned short* gRow1 = B0b + (long long)(n0 + (wave + 4) * 16 + srow) * HID_ + sko;
  const unsigned short* uRow0 = B1b + (long long)(n0 + wave * 16       + srow) * HID_ + sko;
  const unsigned short* uRow1 = B1b + (long long)(n0 + (wave + 4) * 16 + srow) * HID_ + sko;
  const int dst0 = (wave * 16) * 32, dst1 = ((wave + 4) * 16) * 32;

  gload16(aRow0, &As[0][dst0]);
  gload16(aRow1, &As[0][dst1]);
  gload16(gRow0, &B0s[0][dst0]);
  gload16(gRow1, &B0s[0][dst1]);
  gload16(uRow0, &B1s[0][dst0]);
  gload16(uRow1, &B1s[0][dst1]);

  int cur = 0;
  for (int kk = 0; kk < HID_; kk += 32, cur ^= 1) {
    __syncthreads();
    if (kk + 32 < HID_) {
      const int nxt = cur ^ 1, k2 = kk + 32;
      gload16(aRow0 + k2, &As[nxt][dst0]);
      gload16(aRow1 + k2, &As[nxt][dst1]);
      gload16(gRow0 + k2, &B0s[nxt][dst0]);
      gload16(gRow1 + k2, &B0s[nxt][dst1]);
      gload16(uRow0 + k2, &B1s[nxt][dst0]);
      gload16(uRow1 + k2, &B1s[nxt][dst1]);
    }
    bf16x8 af[4], b0[4], b1[4];
    #pragma unroll
    for (int i = 0; i < 4; ++i) {
      af[i] = *reinterpret_cast<const bf16x8*>(&As[cur][(wm + i * 16 + lrow) * 32 + quad * 8]);
      b0[i] = *reinterpret_cast<const bf16x8*>(&B0s[cur][(wn + i * 16 + lrow) * 32 + quad * 8]);
      b1[i] = *reinterpret_cast<const bf16x8*>(&B1s[cur][(wn + i * 16 + lrow) * 32 + quad * 8]);
    }
    #pragma unroll
    for (int i = 0; i < 4; ++i)
      #pragma unroll
      for (int j = 0; j < 4; ++j) {
        acc0[i][j] = __builtin_amdgcn_mfma_f32_16x16x32_bf16(af[i], b0[j], acc0[i][j], 0, 0, 0);
        acc1[i][j] = __builtin_amdgcn_mfma_f32_16x16x32_bf16(af[i], b1[j], acc1[i][j], 0, 0, 0);
      }
  }

  #pragma unroll
  for (int mi = 0; mi < 4; ++mi)
    #pragma unroll
    for (int r = 0; r < 4; ++r) {
      const int gm = m0 + wm + mi * 16 + quad * 4 + r;
      const float rwv = rw[(long long)gm * E_ + zb];
      #pragma unroll
      for (int ni = 0; ni < 4; ++ni) {
        const int gn = n0 + wn + ni * 16 + lrow;
        const float v0 = acc0[mi][ni][r];
        const float v1 = acc1[mi][ni][r];
        const float sg = v0 / (1.f + __expf(-v0));      // silu(gate)
        out0[(long long)gm * IM_ + gn] = f32_to_bf16(sg * v1 * rwv);
      }
    }
}

// ====== v4 pipelined GEMM: hoisted addressing + even-spread staging ========
// BM=256 x BN=128, BK=64, 512 threads = 8 waves (4M x 2N), 16 MFMA/phase.
// All per-phase address math reduced to pointer+=128 / offset^64: staging
// pointers and ds_read byte offsets are precomputed once (HK-style).
//
// DUAL (A[2] 64K, B0[2] 32K, B1[2] 32K = 128 KiB), 4 phases/tile, 2 gload/ph:
//   ph0: rd A.k0,B0.k0 | st B0(T+1)   | BAR lgk0 MFMA acc0(a0) BAR
//   ph1: rd A.k1,B0.k1 | st B1(T+1)   | BAR lgk0 MFMA acc0(a1) BAR
//   ph2: rd B1.k0      | st Ah0(T+2)  | BAR lgk0 MFMA acc1(a0) BAR
//   ph3: rd B1.k1      | st Ah1(T+2)  | vmcnt(4) BAR lgk0 MFMA acc1(a1) BAR
//   vmcnt(4) at ph3 drains A(T+1),B0(T+1),B1(T+1); keeps A(T+2) in flight.
// SINGLE (+PAIRK): A[3] 96K + B[3] 48K = 144 KiB triple-buffered, 2 ph/tile:
//   ph0: rd A.k0,B.k0 | st B(T+2), Ah0(T+2) | BAR lgk0 MFMA BAR
//   ph1: rd A.k1,B.k1 | st Ah1(T+2) | vmcnt(6) BAR lgk0 MFMA BAR
//   vmcnt(6) keeps exactly tile T+2's 6 loads in flight (2-phase distance).
// Triple buffering makes stage-vs-read WAR structurally impossible.
#define EPI5_GU   0   // out0 = bf16(silu(acc0)*acc1*rw[token][expert]), ld IM_
#define EPI5_QK   1   // out0/out1 = bf16(elu(acc)+1), ld HID_
#define EPI5_DOWN 2   // o_f32 += acc0, ld HID_
#define EPI5_WO   3   // o_f32 = acc0 + add_src, ld HID_
template<bool DUAL, int EPI, int KTOT, int KROW, bool PAIRK>
__global__ __launch_bounds__(512, 2) void gemm6_k(
    const unsigned short* A0, const unsigned short* A1,
    const unsigned short* B0b, const unsigned short* B1b,
    const float* __restrict__ rw, int expert,
    unsigned short* out0, unsigned short* out1,
    float* o_f32, const float* add_src)
{
  constexpr int NT  = KTOT / 64;
  constexpr int NT2 = NT / 2;
  __shared__ unsigned short smem[DUAL ? 65536 : 73728];

  const int t = threadIdx.x, wave = t >> 6, lane = t & 63;
  const int lrow = lane & 15, quad = lane >> 4;
  const int wrow0 = (wave >> 1) * 64;   // 0..192
  const int wcol0 = (wave & 1) * 64;    // 0/64

  int bx, by;
  swizzle_xy(bx, by);
  const int m0 = by * 256, n0 = bx * 128;

  const int r8  = lane >> 3;
  const int csw = ((lane & 7) ^ r8) << 4;   // pre-swizzled global byte col

  // ---- hoisted staging pointers: advance +128 B per staged K-tile ----
  const char* pA[4]; const char* qA[4];
  const char* pB0[2]; const char* pB1[2];
  #pragma unroll
  for (int h = 0; h < 2; ++h)
    #pragma unroll
    for (int i = 0; i < 2; ++i) {
      const int row = m0 + h * 128 + wave * 16 + i * 8 + r8;
      pA[h * 2 + i] = (const char*)(A0 + (size_t)row * KROW) + csw;
      if constexpr (PAIRK) qA[h * 2 + i] = (const char*)(A1 + (size_t)row * KROW) + csw;
    }
  #pragma unroll
  for (int i = 0; i < 2; ++i) {
    const int row = n0 + wave * 16 + i * 8 + r8;
    pB0[i] = (const char*)(B0b + (size_t)row * KROW) + csw;
    if constexpr (DUAL || PAIRK) pB1[i] = (const char*)(B1b + (size_t)row * KROW) + csw;
  }

  // LDS dst slots (elements; wave-uniform within each gload)
  const int dAe[4] = { wave * 1024, wave * 1024 + 512,
                       8192 + wave * 1024, 8192 + wave * 1024 + 512 };
  const int dBe[2] = { wave * 1024, wave * 1024 + 512 };

  auto stA_h = [&](int h, int bufAel) {
    #pragma unroll
    for (int i = 0; i < 2; ++i) {
      const int j = h * 2 + i;
      gload16((const unsigned short*)pA[j], &smem[bufAel + dAe[j]]);
      pA[j] += 128;
    }
  };
  auto stB_ = [&](const char** pB, int bel) {
    #pragma unroll
    for (int i = 0; i < 2; ++i) {
      gload16((const unsigned short*)pB[i], &smem[bel + dBe[i]]);
      pB[i] += 128;
    }
  };

  // ---- hoisted ds_read byte offsets (per-thread constants) ----
  const int xr = (lane & 7) << 4;
  int roA[4], roB[4];
  #pragma unroll
  for (int mi = 0; mi < 4; ++mi)
    roA[mi] = (wrow0 >> 7) * 16384 + ((wrow0 & 64) + mi * 16 + lrow) * 128
              + ((quad * 16) ^ xr);
  #pragma unroll
  for (int nj = 0; nj < 4; ++nj)
    roB[nj] = (wcol0 + nj * 16 + lrow) * 128 + ((quad * 16) ^ xr);

  auto readA_ = [&](bf16x8* o, int aByte, int ks) {
    const char* base = (const char*)smem + aByte;
    #pragma unroll
    for (int mi = 0; mi < 4; ++mi)
      o[mi] = *(const bf16x8*)(base + (roA[mi] ^ (ks * 64)));
  };
  auto readB_ = [&](bf16x8* o, int bByte, int ks) {
    const char* base = (const char*)smem + bByte;
    #pragma unroll
    for (int nj = 0; nj < 4; ++nj)
      o[nj] = *(const bf16x8*)(base + (roB[nj] ^ (ks * 64)));
  };

  f32x4 acc0[4][4] = {};
  f32x4 acc1[4][4] = {};
  auto mm = [&](f32x4 (&ac)[4][4], const bf16x8* aF, const bf16x8* bFr) {
    #pragma unroll
    for (int mi = 0; mi < 4; ++mi)
      #pragma unroll
      for (int nj = 0; nj < 4; ++nj)
        ac[mi][nj] = __builtin_amdgcn_mfma_f32_16x16x32_bf16(aF[mi], bFr[nj], ac[mi][nj], 0, 0, 0);
  };

  bf16x8 a0[4], a1[4], bF[4];

  if constexpr (DUAL) {
    // LDS map (elements): A[buf]=buf*16384; B0=32768+buf*8192; B1=49152+buf*8192
    // prologue queue: [A(0)4, B0(0)2, B1(0)2, A(1)4] -> vmcnt(4) keeps A(1)
    stA_h(0, 0); stA_h(1, 0);
    stB_(pB0, 32768); stB_(pB1, 49152);
    stA_h(0, 16384); stA_h(1, 16384);
    vwait<4>();
    __builtin_amdgcn_s_barrier();

    for (int T = 0; T < NT; ++T) {
      const int c = T & 1, cn = c ^ 1;
      const int aB  = c * 32768;            // A buf, bytes
      const int b0B = 65536 + c * 16384;    // B0 buf, bytes
      const int b1B = 98304 + c * 16384;    // B1 buf, bytes
      // ph0: acc0 += a0 * B0.k0 | stage B0(T+1)
      readA_(a0, aB, 0); readB_(bF, b0B, 0);
      if (T + 1 < NT) stB_(pB0, 32768 + cn * 8192);
      __builtin_amdgcn_s_barrier();
      lgk0();
      __builtin_amdgcn_s_setprio(1); mm(acc0, a0, bF); __builtin_amdgcn_s_setprio(0);
      __builtin_amdgcn_s_barrier();
      // ph1: acc0 += a1 * B0.k1 | stage B1(T+1)
      readA_(a1, aB, 1); readB_(bF, b0B, 1);
      if (T + 1 < NT) stB_(pB1, 49152 + cn * 8192);
      __builtin_amdgcn_s_barrier();
      lgk0();
      __builtin_amdgcn_s_setprio(1); mm(acc0, a1, bF); __builtin_amdgcn_s_setprio(0);
      __builtin_amdgcn_s_barrier();
      // ph2: acc1 += a0 * B1.k0 | stage Ah0(T+2) (A reads of this buf done ph1)
      readB_(bF, b1B, 0);
      if (T + 2 < NT) stA_h(0, c * 16384);
      __builtin_amdgcn_s_barrier();
      lgk0();
      __builtin_amdgcn_s_setprio(1); mm(acc1, a0, bF); __builtin_amdgcn_s_setprio(0);
      __builtin_amdgcn_s_barrier();
      // ph3: acc1 += a1 * B1.k1 | stage Ah1(T+2) | counted wait
      readB_(bF, b1B, 1);
      if (T + 2 < NT) { stA_h(1, c * 16384); vwait<4>(); }
      else            { vwait<0>(); }
      __builtin_amdgcn_s_barrier();
      lgk0();
      __builtin_amdgcn_s_setprio(1); mm(acc1, a1, bF); __builtin_amdgcn_s_setprio(0);
      __builtin_amdgcn_s_barrier();
    }
  } else {
    // LDS map (elements): A[buf]=buf*16384 (3 bufs); B=49152+buf*8192 (3 bufs)
    // prologue queue: [B(0)2, A(0)4, B(1)2, A(1)4] -> vmcnt(6) keeps tile-1's 6
    stB_(pB0, 49152); stA_h(0, 0); stA_h(1, 0);
    stB_(pB0, 49152 + 8192); stA_h(0, 16384); stA_h(1, 16384);
    vwait<6>();
    __builtin_amdgcn_s_barrier();

    int ab = 0, tg = 2;   // read-buf idx (T%3), stage-target idx ((T+2)%3)
    for (int T = 0; T < NT; ++T) {
      const int aB = ab * 32768;            // bytes
      const int bB = 98304 + ab * 16384;    // bytes
      const int aT = tg * 16384;            // elements
      const int bT = 49152 + tg * 8192;     // elements
      // ph0
      readA_(a0, aB, 0); readB_(bF, bB, 0);
      if (PAIRK && T + 2 == NT2) {          // switch to second K-half matrices
        pB0[0] = pB1[0]; pB0[1] = pB1[1];
        pA[0] = qA[0]; pA[1] = qA[1]; pA[2] = qA[2]; pA[3] = qA[3];
      }
      if (T + 2 < NT) { stB_(pB0, bT); stA_h(0, aT); }
      __builtin_amdgcn_s_barrier();
      lgk0();
      __builtin_amdgcn_s_setprio(1); mm(acc0, a0, bF); __builtin_amdgcn_s_setprio(0);
      __builtin_amdgcn_s_barrier();
      // ph1
      readA_(a1, aB, 1); readB_(bF, bB, 1);
      if (T + 2 < NT) { stA_h(1, aT); vwait<6>(); }
      else            { vwait<0>(); }
      __builtin_amdgcn_s_barrier();
      lgk0();
      __builtin_amdgcn_s_setprio(1); mm(acc0, a1, bF); __builtin_amdgcn_s_setprio(0);
      __builtin_amdgcn_s_barrier();
      if (++ab == 3) ab = 0;
      if (++tg == 3) tg = 0;
    }
  }

  // epilogue: D row = quad*4+r, col = lane&15
  #pragma unroll
  for (int mi = 0; mi < 4; ++mi) {
    #pragma unroll
    for (int r = 0; r < 4; ++r) {
      const int gm = m0 + wrow0 + mi * 16 + quad * 4 + r;
      float rwv = 0.f;
      if (EPI == EPI5_GU) rwv = rw[(size_t)gm * E_ + expert];
      #pragma unroll
      for (int nj = 0; nj < 4; ++nj) {
        const int gn = n0 + wcol0 + nj * 16 + lrow;
        const float v0 = acc0[mi][nj][r];
        if (EPI == EPI5_GU) {
          const float v1 = acc1[mi][nj][r];
          const float sg = v0 / (1.f + __expf(-v0));
          out0[(size_t)gm * IM_ + gn] = f32_to_bf16(sg * v1 * rwv);
        } else if (EPI == EPI5_QK) {
          const float v1 = acc1[mi][nj][r];
          out0[(size_t)gm * HID_ + gn] = f32_to_bf16(v0 > 0.f ? v0 + 1.f : __expf(v0));
          out1[(size_t)gm * HID_ + gn] = f32_to_bf16(v1 > 0.f ? v1 + 1.f : __expf(v1));
        } else if (EPI == EPI5_DOWN) {
          o_f32[(size_t)gm * HID_ + gn] += v0;
        } else {  // EPI5_WO
          const size_t idx = (size_t)gm * HID_ + gn;
          o_f32[idx] = v0 + add_src[idx];
        }
      }
    }
  }
}

// fp32 [R][C] -> bf16 [C][R]; z selects among 4 sources, dst stride R*C
__global__ void transpose_cast4_k(const float* s0, const float* s1,
                                  const float* s2, const float* s3,
                                  unsigned short* __restrict__ out, int R, int C)
{
  __shared__ float tile[32][33];
  const int z = blockIdx.z;
  const float* in = (z == 0) ? s0 : (z == 1) ? s1 : (z == 2) ? s2 : s3;
  unsigned short* o = out + (long long)z * R * C;
  const int c0 = blockIdx.x * 32, r0 = blockIdx.y * 32;
  const int tx = threadIdx.x, ty = threadIdx.y;
  #pragma unroll
  for (int i = 0; i < 32; i += 8)
    tile[ty + i][tx] = in[(long long)(r0 + ty + i) * C + c0 + tx];
  __syncthreads();
  #pragma unroll
  for (int i = 0; i < 32; i += 8)
    o[(long long)(c0 + ty + i) * R + r0 + tx] = f32_to_bf16(tile[tx][ty + i]);
}

// fp32 [R][C] -> bf16 [C][R]; z<4: srcA/dstA expert z; z>=4: srcB/dstB
__global__ void transpose_cast2x4_k(const float* __restrict__ sA,
                                    const float* __restrict__ sB,
                                    unsigned short* __restrict__ dA,
                                    unsigned short* __restrict__ dB,
                                    int R, int C)
{
  __shared__ float tile[32][33];
  const int z = blockIdx.z;
  const long long eo = (long long)(z & 3) * R * C;
  const float* in = ((z < 4) ? sA : sB) + eo;
  unsigned short* o = ((z < 4) ? dA : dB) + eo;
  const int c0 = blockIdx.x * 32, r0 = blockIdx.y * 32;
  const int tx = threadIdx.x, ty = threadIdx.y;
  #pragma unroll
  for (int i = 0; i < 32; i += 8)
    tile[ty + i][tx] = in[(long long)(r0 + ty + i) * C + c0 + tx];
  __syncthreads();
  #pragma unroll
  for (int i = 0; i < 32; i += 8)
    o[(long long)(c0 + ty + i) * R + r0 + tx] = f32_to_bf16(tile[tx][ty + i]);
}

// fp32 [R][C] -> bf16 [C][R], batched over z (single base, stride R*C)
__global__ void transpose_cast_k(const float* __restrict__ in,
                                 unsigned short* __restrict__ out, int R, int C)
{
  __shared__ float tile[32][33];
  const long long bo = (long long)blockIdx.z * R * C;
  const int c0 = blockIdx.x * 32, r0 = blockIdx.y * 32;
  const int tx = threadIdx.x, ty = threadIdx.y;
  #pragma unroll
  for (int i = 0; i < 32; i += 8)
    tile[ty + i][tx] = in[bo + (long long)(r0 + ty + i) * C + c0 + tx];
  __syncthreads();
  #pragma unroll
  for (int i = 0; i < 32; i += 8)
    out[bo + (long long)(c0 + ty + i) * R + r0 + tx] = f32_to_bf16(tile[tx][ty + i]);
}

// rmsnorm row (HID=1024) + weight + bf16 cast; one block per token
__global__ __launch_bounds__(256) void rmsnorm_cast_k(
    const float* __restrict__ x, const float* __restrict__ w,
    unsigned short* __restrict__ out)
{
  __shared__ float red[4];
  const int row = blockIdx.x, t = threadIdx.x;
  const float4 v = reinterpret_cast<const float4*>(x + (long long)row * HID_)[t];
  float ss = v.x * v.x + v.y * v.y + v.z * v.z + v.w * v.w;
  #pragma unroll
  for (int off = 32; off > 0; off >>= 1) ss += __shfl_down(ss, off, 64);
  if ((t & 63) == 0) red[t >> 6] = ss;
  __syncthreads();
  ss = red[0] + red[1] + red[2] + red[3];
  const float inv = rsqrtf(ss * (1.0f / HID_) + 1e-6f);
  const float4 wv = reinterpret_cast<const float4*>(w)[t];
  ushort4 o;
  o.x = f32_to_bf16(v.x * inv * wv.x);
  o.y = f32_to_bf16(v.y * inv * wv.y);
  o.z = f32_to_bf16(v.z * inv * wv.z);
  o.w = f32_to_bf16(v.w * inv * wv.w);
  reinterpret_cast<ushort4*>(out + (long long)row * HID_)[t] = o;
}

// softmax over a 2048-wide fp32 row; writes P bf16 IN PLACE over the row
__global__ __launch_bounds__(256) void softmax_rows_k(float* __restrict__ scores)
{
  __shared__ float red[4];
  const long long rbase = ((long long)blockIdx.y * S_ + blockIdx.x) * S_;
  float* row = scores + rbase;
  const int t = threadIdx.x;
  float v[8];
  #pragma unroll
  for (int i = 0; i < 8; ++i) v[i] = row[t + i * 256];
  float m = v[0];
  #pragma unroll
  for (int i = 1; i < 8; ++i) m = fmaxf(m, v[i]);
  #pragma unroll
  for (int off = 32; off > 0; off >>= 1) m = fmaxf(m, __shfl_down(m, off, 64));
  if ((t & 63) == 0) red[t >> 6] = m;
  __syncthreads();
  m = fmaxf(fmaxf(red[0], red[1]), fmaxf(red[2], red[3]));
  __syncthreads();
  float s = 0.f;
  #pragma unroll
  for (int i = 0; i < 8; ++i) { v[i] = __expf(v[i] - m); s += v[i]; }
  #pragma unroll
  for (int off = 32; off > 0; off >>= 1) s += __shfl_down(s, off, 64);
  if ((t & 63) == 0) red[t >> 6] = s;
  __syncthreads();
  const float inv = 1.0f / (red[0] + red[1] + red[2] + red[3]);
  unsigned short* prow = reinterpret_cast<unsigned short*>(scores) + rbase * 2;
  #pragma unroll
  for (int i = 0; i < 8; ++i) prow[t + i * 256] = f32_to_bf16(v[i] * inv);
}

// router: fp32 rms(h1)*ln2w @ router_w + b, softmax over E=4. One wave/token.
__global__ __launch_bounds__(256) void router_k(
    const float* __restrict__ h1, const float* __restrict__ ln2w,
    const float* __restrict__ rwgt, const float* __restrict__ rbias,
    float* __restrict__ rw)
{
  const int wv = threadIdx.x >> 6, lane = threadIdx.x & 63;
  const long long m = (long long)blockIdx.x * 4 + wv;
  const float* xr = h1 + m * HID_;
  float xv[16];
  float ss = 0.f;
  #pragma unroll
  for (int i = 0; i < 16; ++i) { xv[i] = xr[lane + i * 64]; ss += xv[i] * xv[i]; }
  #pragma unroll
  for (int off = 32; off > 0; off >>= 1) ss += __shfl_down(ss, off, 64);
  ss = __shfl(ss, 0, 64);
  const float inv = rsqrtf(ss * (1.0f / HID_) + 1e-6f);
  float l0 = 0, l1 = 0, l2 = 0, l3 = 0;
  #pragma unroll
  for (int i = 0; i < 16; ++i) {
    const int k = lane + i * 64;
    const float xn = xv[i] * inv * ln2w[k];
    const float4 wr = reinterpret_cast<const float4*>(rwgt)[k];
    l0 += xn * wr.x; l1 += xn * wr.y; l2 += xn * wr.z; l3 += xn * wr.w;
  }
  #pragma unroll
  for (int off = 32; off > 0; off >>= 1) {
    l0 += __shfl_down(l0, off, 64);
    l1 += __shfl_down(l1, off, 64);
    l2 += __shfl_down(l2, off, 64);
    l3 += __shfl_down(l3, off, 64);
  }
  if (lane == 0) {
    l0 += rbias[0]; l1 += rbias[1]; l2 += rbias[2]; l3 += rbias[3];
    const float mx = fmaxf(fmaxf(l0, l1), fmaxf(l2, l3));
    const float e0 = __expf(l0 - mx), e1 = __expf(l1 - mx);
    const float e2 = __expf(l2 - mx), e3 = __expf(l3 - mx);
    const float is = 1.0f / (e0 + e1 + e2 + e3);
    reinterpret_cast<float4*>(rw)[m] = make_float4(e0 * is, e1 * is, e2 * is, e3 * is);
  }
}

// balance loss: single block, deterministic
__global__ __launch_bounds__(256) void balance_k(const float* __restrict__ rw,
                                                 float* __restrict__ out_scalar)
{
  __shared__ float red[4];
  float acc = 0.f;
  for (int it = threadIdx.x; it < S_ * E_; it += 256) {
    const int s = it >> 2, e = it & 3;
    float mr = 0.f;
    #pragma unroll
    for (int b = 0; b < B_; ++b) mr += rw[((long long)b * S_ + s) * E_ + e];
    mr *= (1.0f / B_);
    const float d = mr - 1.0f / E_;
    acc += d * d;
  }
  #pragma unroll
  for (int off = 32; off > 0; off >>= 1) acc += __shfl_down(acc, off, 64);
  if ((threadIdx.x & 63) == 0) red[threadIdx.x >> 6] = acc;
  __syncthreads();
  if (threadIdx.x == 0)
    out_scalar[0] = (red[0] + red[1] + red[2] + red[3]) * (0.01f / (S_ * E_));
}

extern "C" void kernel_launch(void* const* d_in, const int* in_sizes, int n_in,
                              void* d_out, int out_size, void* d_ws, size_t ws_size,
                              hipStream_t stream)
{
  const float* hidden   = (const float*)d_in[0];
  const float* ln1w     = (const float*)d_in[1];
  const float* wq       = (const float*)d_in[2];
  const float* wk       = (const float*)d_in[3];
  const float* wv       = (const float*)d_in[4];
  const float* wo       = (const float*)d_in[5];
  const float* ln2w     = (const float*)d_in[6];
  const float* router_w = (const float*)d_in[7];
  const float* router_b = (const float*)d_in[8];
  const float* gate_w   = (const float*)d_in[9];
  const float* up_w     = (const float*)d_in[10];
  const float* down_w   = (const float*)d_in[11];
  float* out = (float*)d_out;   // h1 lives here; MoE accumulates in place

  char* ws = (char*)d_ws;
  size_t off = 0;
  auto carve = [&](size_t bytes) {
    off = (off + 255) & ~(size_t)255;
    char* p = ws + off;
    off += bytes;
    return p;
  };
  unsigned short* wqT   = (unsigned short*)carve((size_t)HID_ * HID_ * 2);  // 2 MiB
  unsigned short* wkT   = (unsigned short*)carve((size_t)HID_ * HID_ * 2);
  unsigned short* wvT   = (unsigned short*)carve((size_t)HID_ * HID_ * 2);
  unsigned short* woT   = (unsigned short*)carve((size_t)HID_ * HID_ * 2);
  unsigned short* x_bf  = (unsigned short*)carve((size_t)M_ * HID_ * 2);    // 16 MiB, reused as o_bf
  unsigned short* qb    = (unsigned short*)carve((size_t)M_ * HID_ * 2);    // 16 MiB, reused as x2_bf
  unsigned short* kb    = (unsigned short*)carve((size_t)M_ * HID_ * 2);    // 16 MiB \ gu0 (32 MiB)
  unsigned short* vT    = (unsigned short*)carve((size_t)M_ * HID_ * 2);    // 16 MiB /
  float*          rwbuf = (float*)carve((size_t)M_ * E_ * 4);               // 128 KiB
  char*           ubase = carve((size_t)NHG_ * S_ * S_ * 4);                // 64 MiB union
  float*          scores = (float*)ubase;
  unsigned short* gateT = (unsigned short*)(ubase);                          // 16 MiB
  unsigned short* upT   = (unsigned short*)(ubase + (size_t)16 * 1024 * 1024);
  unsigned short* downT = (unsigned short*)(ubase + (size_t)32 * 1024 * 1024);
  unsigned short* o_bf  = x_bf;
  unsigned short* x2_bf = qb;
  unsigned short* gu0   = kb;   // spans kb+vT = 32 MiB
  // second 32 MiB buffer: gu of the odd expert (down pair reads both)
  unsigned short* gu1   = (unsigned short*)carve((size_t)M_ * IM_ * 2);     // +32 MiB
  const bool paired = (ws_size >= off);

  const dim3 blk256(256), blk512(512), blkT(32, 8);

  // 1) attention weights -> bf16 B^T (one dispatch, z=4)
  transpose_cast4_k<<<dim3(32, 32, 4), blkT, 0, stream>>>(wq, wk, wv, wo, wqT, HID_, HID_);

  // 2) x = bf16(rms(hidden, ln1_w))
  rmsnorm_cast_k<<<M_, blk256, 0, stream>>>(hidden, ln1w, x_bf);

  // 3) Q+K fused (dual v4, shared A staging, elu+1 epilogue); V transposed
  gemm6_k<true, EPI5_QK, 1024, 1024, false><<<dim3(8, 32, 1), blk512, 0, stream>>>(
      x_bf, nullptr, wqT, wkT, nullptr, 0, qb, kb, nullptr, nullptr);
  {
    EpiAux a{}; a.c_bf16 = vT;
    gemm_bf16k<EPI_VT><<<dim3(8, 64, 1), blk256, 0, stream>>>(
        x_bf, HID_, 0, 0, 0, wvT, HID_, 0, 0, 0, 0, 0, 0, HID_, a);
  }

  // 4) attention, NHG_=4 heads per group; scores slab reused per group
  for (int grp = 0; grp < 16 / NHG_; ++grp) {
    EpiAux as{}; as.c_f32 = scores; as.ldc = S_; as.strideCz = (long long)S_ * S_;
    gemm_bf16k<EPI_F32><<<dim3(16, 16, NHG_), blk256, 0, stream>>>(
        qb, HID_, (long long)S_ * HID_, HD_, grp * NHG_,
        kb, HID_, (long long)S_ * HID_, HD_, grp * NHG_,
        2, 3, 0, HD_, as);
    softmax_rows_k<<<dim3(S_, NHG_, 1), blk256, 0, stream>>>(scores);
    EpiAux ap{}; ap.c_bf16 = o_bf;
    gemm_bf16k<EPI_PV_O><<<dim3(2, 16, NHG_), blk256, 0, stream>>>(
        (const unsigned short*)scores, 2 * S_, (long long)S_ * 2 * S_, 0, 0,
        vT, S_, (long long)HD_ * S_, 0, grp * NHG_,
        0, 0, grp * NHG_, S_, ap);
  }

  // 5) MoE weights -> bf16 B^T into the now-dead scores slab
  transpose_cast2x4_k<<<dim3(64, 32, 8), blkT, 0, stream>>>(
      gate_w, up_w, gateT, upT, HID_, IM_);
  transpose_cast_k<<<dim3(32, 64, E_), blkT, 0, stream>>>(down_w, downT, IM_, HID_);

  // 6) h1 = hidden + O @ wo (v4 single pipeline), written straight into d_out
  gemm6_k<false, EPI5_WO, 1024, 1024, false><<<dim3(8, 32, 1), blk512, 0, stream>>>(
      o_bf, nullptr, woT, nullptr, nullptr, 0, nullptr, nullptr, out, hidden);

  // 7) x2 = bf16(rms(h1, ln2_w)); router (fp32); balance loss scalar
  rmsnorm_cast_k<<<M_, blk256, 0, stream>>>(out, ln2w, x2_bf);
  router_k<<<M_ / 4, blk256, 0, stream>>>(out, ln2w, router_w, router_b, rwbuf);
  balance_k<<<1, blk256, 0, stream>>>(rwbuf, out + (size_t)M_ * HID_);

  // 8) dense MoE: fused dual-B GU (silu*u*rw folded) per expert on the v4
  //    kernel; expert-paired down via PAIRK K-concat (K=4096).
  const size_t wsz = (size_t)IM_ * HID_;
  if (paired) {
    for (int p = 0; p < 2; ++p) {
      const int e0 = 2 * p, e1 = e0 + 1;
      gemm6_k<true, EPI5_GU, 1024, 1024, false><<<dim3(16, 32, 1), blk512, 0, stream>>>(
          x2_bf, nullptr, gateT + (size_t)e0 * wsz, upT + (size_t)e0 * wsz,
          rwbuf, e0, gu0, nullptr, nullptr, nullptr);
      gemm6_k<true, EPI5_GU, 1024, 1024, false><<<dim3(16, 32, 1), blk512, 0, stream>>>(
          x2_bf, nullptr, gateT + (size_t)e1 * wsz, upT + (size_t)e1 * wsz,
          rwbuf, e1, gu1, nullptr, nullptr, nullptr);
      gemm6_k<false, EPI5_DOWN, 4096, 2048, true><<<dim3(8, 32, 1), blk512, 0, stream>>>(
          gu0, gu1, downT + (size_t)e0 * wsz, downT + (size_t)e1 * wsz,
          nullptr, 0, nullptr, nullptr, out, nullptr);
    }
  } else {
    for (int i = 0; i < E_; ++i) {
      gemm_dual_k<EPI2_GU><<<dim3(16, 64, 1), blk256, 0, stream>>>(
          x2_bf, gateT + (size_t)i * wsz, upT + (size_t)i * wsz, i, gu0, nullptr, rwbuf);
      EpiAux ad{}; ad.out2 = out;
      gemm_bf16k<EPI_DOWN><<<dim3(8, 64, 1), blk256, 0, stream>>>(
          gu0, IM_, 0, 0, 0, downT + (size_t)i * wsz, IM_, 0, 0, 0,
          0, 0, 0, IM_, ad);
    }
  }
}